// Round 20
// baseline (662.574 us; speedup 1.0000x reference)
//
#include <hip/hip_runtime.h>

typedef __attribute__((ext_vector_type(8))) __bf16 bf16x8;
typedef __attribute__((ext_vector_type(4))) float f32x4;
typedef __attribute__((ext_vector_type(4))) unsigned short u16x4;
typedef __attribute__((ext_vector_type(8))) unsigned short u16x8;

#define MFMA_BF16 __builtin_amdgcn_mfma_f32_16x16x32_bf16

__device__ __forceinline__ unsigned short f2bf(float f) {
  union { float f; unsigned u; } v; v.f = f;
  unsigned r = v.u + 0x7FFFu + ((v.u >> 16) & 1u);
  return (unsigned short)(r >> 16);
}

__device__ __forceinline__ void gload16(const void* g, void* l) {
  __builtin_amdgcn_global_load_lds(
      (const __attribute__((address_space(1))) unsigned int*)g,
      (__attribute__((address_space(3))) unsigned int*)l, 16, 0, 0);
}

// ---- fused cast: all 6 fp32->bf16 conversions in one launch ----
__device__ __forceinline__ void cast8(const float* __restrict__ in,
                                      unsigned short* __restrict__ out, long i) {
  long base = i * 8;
  float4 a = *(const float4*)(in + base);
  float4 b = *(const float4*)(in + base + 4);
  u16x8 o;
  o[0] = f2bf(a.x); o[1] = f2bf(a.y); o[2] = f2bf(a.z); o[3] = f2bf(a.w);
  o[4] = f2bf(b.x); o[5] = f2bf(b.y); o[6] = f2bf(b.z); o[7] = f2bf(b.w);
  *(u16x8*)(out + base) = o;
}

__global__ void __launch_bounds__(256) cast_all(
    const float* __restrict__ x, const float* __restrict__ wqkv,
    const float* __restrict__ wq, const float* __restrict__ wkv,
    const float* __restrict__ wpn, const float* __restrict__ wpa,
    unsigned short* __restrict__ xb, unsigned short* __restrict__ wqkvb,
    unsigned short* __restrict__ wqb, unsigned short* __restrict__ wkvb,
    unsigned short* __restrict__ wpnb, unsigned short* __restrict__ wpab) {
  const long c0 = 3801600, c1 = 4299264, c2 = 4465152, c3 = 4796928,
             c4 = 4962816, c5 = 5128704;
  long i = (long)blockIdx.x * 256 + threadIdx.x;
  if (i >= c5) return;
  if (i < c0)      cast8(x,    xb,    i);
  else if (i < c1) cast8(wqkv, wqkvb, i - c0);
  else if (i < c2) cast8(wq,   wqb,   i - c1);
  else if (i < c3) cast8(wkv,  wkvb,  i - c2);
  else if (i < c4) cast8(wpn,  wpnb,  i - c3);
  else             cast8(wpa,  wpab,  i - c4);
}

// row remapping: 0 = identity, 1 = b*825 + 57 + (m % 768), 2 = b*825 + (m % 57),
//                3 = b*825 + 56 + (m % 769)
template <int REMAP>
__device__ __forceinline__ long remap_row(int m) {
  if (REMAP == 1) { int b = m / 768; return (long)b * 825 + 57 + (m - b * 768); }
  if (REMAP == 2) { int b = m / 57;  return (long)b * 825 + (m - b * 57); }
  if (REMAP == 3) { int b = m / 769; return (long)b * 825 + 56 + (m - b * 769); }
  return m;
}

// ===== 256x256 tile, BK=64, 8-wave, 2-phase/K-tile, register-pipelined fA =====
// r17-verified T19 interleave {1 ds_read(fA), 4 MFMA} x 8 then 4 fB ds_reads,
// plus T5 setprio(1) around the MFMA cluster (SGB interleave creates the wave
// role-split that setprio arbitrates).
template <int REMAP, bool PROJ>
__device__ __forceinline__ void gemm_body(unsigned short* L, int orig, int gx, int nwg,
                                          const unsigned short* __restrict__ A,
                                          const unsigned short* __restrict__ Bw,
                                          void* __restrict__ Cout,
                                          const float* __restrict__ bias,
                                          int M, int N) {
  const int K = 1152;
  unsigned short* Al = L;
  unsigned short* Bl = L + 32768;
  int tid = threadIdx.x;
  int lane = tid & 63;
  int wid = tid >> 6;
  int l15 = lane & 15, hi = lane >> 4;
  int wm = wid >> 2, wn = wid & 3;

  // bijective XCD swizzle within this segment
  int q8 = nwg >> 3, r8 = nwg & 7;
  int xcd = orig & 7, off = orig >> 3;
  int wgid = (xcd < r8 ? xcd * (q8 + 1) : r8 * (q8 + 1) + (xcd - r8) * q8) + off;
  int bn = wgid % gx, bm = wgid / gx;
  int m0 = bm * 256, n0 = bn * 256;

  // staging geometry: thread stages 16B at slot-bytes tid*16 and tid*16+8192
  int rlo = tid >> 2;
  int cg = ((tid & 3) - (tid >> 3)) & 3;
  int ma0 = m0 + rlo;       if (ma0 > M - 1) ma0 = M - 1;
  int ma1 = m0 + rlo + 128; if (ma1 > M - 1) ma1 = M - 1;
  const unsigned short* aptr0 = A + remap_row<REMAP>(ma0) * K + cg * 8;
  const unsigned short* aptr1 = A + remap_row<REMAP>(ma1) * K + cg * 8;
  int nb0 = n0 + rlo;       if (nb0 > N - 1) nb0 = N - 1;
  int nb1 = n0 + rlo + 128; if (nb1 > N - 1) nb1 = N - 1;
  const unsigned short* bptr0 = Bw + (long)nb0 * K + cg * 8;
  const unsigned short* bptr1 = Bw + (long)nb1 * K + cg * 8;
  unsigned ldst = (unsigned)tid * 8;

  unsigned short* Ad = Al + ldst;
  unsigned short* Bd = Bl + ldst;

  const int cl = (hi + (l15 >> 1)) & 3;
  const unsigned short* arb[4];
  const unsigned short* brb[4];
#pragma unroll
  for (int f = 0; f < 4; ++f) {
    arb[f] = Al + (wm * 128 + f * 16 + l15) * 32 + cl * 8;
    brb[f] = Bl + (wn * 64 + f * 16 + l15) * 32 + cl * 8;
  }

#define STAGE(P)                                                        \
  {                                                                     \
    gload16(aptr0 + (P) * 32, Ad + (((P) & 3) << 13));                  \
    gload16(aptr1 + (P) * 32, Ad + ((((P) & 3) << 13)) + 4096);         \
    gload16(bptr0 + (P) * 32, Bd + (((P) & 3) << 13));                  \
    gload16(bptr1 + (P) * 32, Bd + ((((P) & 3) << 13)) + 4096);         \
  }
#define READ_FA(P, S)                                                   \
  {                                                                     \
    _Pragma("unroll") for (int f = 0; f < 8; ++f)                       \
        fA[S][f] = *(const bf16x8*)(arb[f & 3] + (((P) & 3) << 13) + (f >> 2) * 2048); \
  }
#define READ_FB(P)                                                      \
  {                                                                     \
    _Pragma("unroll") for (int f = 0; f < 4; ++f)                       \
        fB[f] = *(const bf16x8*)(brb[f] + (((P) & 3) << 13));           \
  }

  STAGE(0); STAGE(1); STAGE(2);
  __builtin_amdgcn_sched_barrier(0);
  asm volatile("s_waitcnt vmcnt(4)" ::: "memory");
  __builtin_amdgcn_s_barrier();
  __builtin_amdgcn_sched_barrier(0);

  bf16x8 fA[2][8];
  bf16x8 fB[4];
  READ_FA(0, 0);
  READ_FB(0);
  f32x4 acc[8][4] = {};

#pragma unroll
  for (int p = 0; p < 36; ++p) {
    const int cur = p & 1;
    if (p < 35) READ_FA(p + 1, cur ^ 1);     // next-phase A frags, independent regs
    __builtin_amdgcn_s_setprio(1);
#pragma unroll
    for (int fm = 0; fm < 8; ++fm)
#pragma unroll
      for (int fn = 0; fn < 4; ++fn)
        acc[fm][fn] = MFMA_BF16(fA[cur][fm], fB[fn], acc[fm][fn], 0, 0, 0);
    __builtin_amdgcn_s_setprio(0);
    if (p < 35) READ_FB(p + 1);              // B frags (WAR-ordered after MFMA)
    if (p <= 32) STAGE(p + 3);
    if (p < 35) {
      // T19: emit {1 fA ds_read, 4 MFMA} x 8, then the 4 fB reads (WAR keeps them late)
#pragma unroll
      for (int g = 0; g < 8; ++g) {
        __builtin_amdgcn_sched_group_barrier(0x100, 1, 0);
        __builtin_amdgcn_sched_group_barrier(0x008, 4, 0);
      }
      __builtin_amdgcn_sched_group_barrier(0x100, 4, 0);
    }
    if (p <= 32)      asm volatile("s_waitcnt vmcnt(4)" ::: "memory");
    else if (p == 33) asm volatile("s_waitcnt vmcnt(0)" ::: "memory");
    if (p < 35) {
      __builtin_amdgcn_sched_barrier(0);
      __builtin_amdgcn_s_barrier();
      __builtin_amdgcn_sched_barrier(0);
    }
  }
#undef STAGE
#undef READ_FA
#undef READ_FB

  // ======== epilogue via per-wave-private LDS region -> coalesced 16B stores ========
  if (!PROJ) {
    unsigned short* reg = L + wid * 8192;
#pragma unroll
    for (int a = 0; a < 8; ++a) {
#pragma unroll
      for (int fn = 0; fn < 4; ++fn) {
        int rbase = a * 16 + hi * 4;
#pragma unroll
        for (int r = 0; r < 4; ++r) {
          int row = rbase + r;
          int ch = (fn * 2 + (l15 >> 3)) ^ (row & 7);
          reg[row * 64 + ch * 8 + (l15 & 7)] = f2bf(acc[a][fn][r]);
        }
      }
    }
#pragma unroll
    for (int i = 0; i < 16; ++i) {
      int rr = i * 8 + (lane >> 3);
      int ch = (lane & 7) ^ (rr & 7);
      u16x8 v = *(const u16x8*)(reg + rr * 64 + ch * 8);
      int m = m0 + wm * 128 + rr;
      int n = n0 + wn * 64 + (lane & 7) * 8;
      if (m < M && n < N)
        *(u16x8*)((unsigned short*)Cout + (long)m * N + n) = v;
    }
  } else {
    float* regf = (float*)L + wid * 4096;
    float bv[4];
#pragma unroll
    for (int fn = 0; fn < 4; ++fn) {
      int n = n0 + wn * 64 + fn * 16 + l15;
      bv[fn] = bias[n < N ? n : N - 1];
    }
#pragma unroll
    for (int half = 0; half < 2; ++half) {
#pragma unroll
      for (int a4 = 0; a4 < 4; ++a4) {
#pragma unroll
        for (int fn = 0; fn < 4; ++fn) {
          int rbase = a4 * 16 + hi * 4;
#pragma unroll
          for (int r = 0; r < 4; ++r)
            regf[(rbase + r) * 64 + fn * 16 + l15] = acc[half * 4 + a4][fn][r] + bv[fn];
        }
      }
#pragma unroll
      for (int i = 0; i < 16; ++i) {
        int rr = i * 4 + (lane >> 4);
        int cc = (lane & 15) * 4;
        f32x4 v = *(const f32x4*)(regf + rr * 64 + cc);
        int m = m0 + wm * 128 + half * 64 + rr;
        int n = n0 + wn * 64 + cc;
        if (m < M && n < N)
          *(f32x4*)((float*)Cout + remap_row<REMAP>(m) * N + n) = v;
      }
      if (half == 0) asm volatile("s_waitcnt lgkmcnt(0)" ::: "memory");
    }
  }
}

// fused front GEMMs: qkv (1344 blocks) | kv (873, trimmed rows) | q_act (40)
__global__ void __launch_bounds__(512, 2) gemm_front(
    const unsigned short* __restrict__ xb, const unsigned short* __restrict__ wqkvb,
    const unsigned short* __restrict__ wkvb, const unsigned short* __restrict__ wqb,
    unsigned short* __restrict__ qkvw, unsigned short* __restrict__ kvw,
    unsigned short* __restrict__ qw) {
  __shared__ unsigned short L[65536];  // 128 KiB, shared by all branches
  int bid = blockIdx.x;
  if (bid < 1344)
    gemm_body<1, false>(L, bid, 14, 1344, xb, wqkvb, qkvw, nullptr, 24576, 3456);
  else if (bid < 2217)
    gemm_body<3, false>(L, bid - 1344, 9, 873, xb, wkvb, kvw, nullptr, 24608, 2304);
  else
    gemm_body<2, false>(L, bid - 2217, 5, 40, xb, wqb, qw, nullptr, 1824, 1152);
}

// fused projections: proj_act (40 blocks, first) | proj_non (480)
__global__ void __launch_bounds__(512, 2) gemm_proj(
    const unsigned short* __restrict__ attnw, const unsigned short* __restrict__ wpnb,
    const unsigned short* __restrict__ wpab, float* __restrict__ out,
    const float* __restrict__ bpn, const float* __restrict__ bpa) {
  __shared__ unsigned short L[65536];
  int bid = blockIdx.x;
  if (bid < 40)
    gemm_body<2, true>(L, bid, 5, 40, attnw, wpab, out, bpa, 1824, 1152);
  else
    gemm_body<1, true>(L, bid - 40, 5, 480, attnw, wpnb, out, bpn, 24576, 1152);
}

// ---- non-act attention: one block per (h, g, b); 4 waves, each owns 64 q rows ----
__global__ void __launch_bounds__(256) attn_non(const unsigned short* __restrict__ qkv,
                                                unsigned short* __restrict__ o) {
  int h = blockIdx.x, g = blockIdx.y, b = blockIdx.z;
  __shared__ unsigned short K_s[128 * 104];
  __shared__ unsigned short V_s[80 * 136];
  __shared__ unsigned short P_s[16 * 16 * 40];
  int tid = threadIdx.x, lane = tid & 63, wid = tid >> 6;
  int l15 = lane & 15, hi = lane >> 4;
  const long base = (long)((b * 3 + g) * 256) * 3456;
  const float SC2 = 0.11785113019775793f * 1.4426950408889634f;

  bf16x8 qf[4][3];
#pragma unroll
  for (int qt = 0; qt < 4; qt++)
#pragma unroll
    for (int ds = 0; ds < 3; ds++) {
      int q = wid * 64 + qt * 16 + l15;
      int d = ds * 32 + hi * 8;
      if (d < 72)
        qf[qt][ds] = *(const bf16x8*)(qkv + base + (long)q * 3456 + h * 72 + d);
      else {
        u16x8 z = {0, 0, 0, 0, 0, 0, 0, 0};
        qf[qt][ds] = __builtin_bit_cast(bf16x8, z);
      }
    }

  f32x4 ot[5][4] = {};
  float lsum[4] = {0.f, 0.f, 0.f, 0.f};

  for (int c0 = 0; c0 < 256; c0 += 128) {
    {
      int r = tid >> 1, hf = tid & 1;
      const unsigned short* src = qkv + base + (long)(c0 + r) * 3456 + (16 + h) * 72 + hf * 48;
      unsigned short* dst = &K_s[r * 104 + hf * 48];
#pragma unroll
      for (int j = 0; j < 6; j++) {
        int col = hf * 48 + j * 8;
        u16x8 v = {0, 0, 0, 0, 0, 0, 0, 0};
        if (col < 72) v = *(const u16x8*)(src + j * 8);
        *(u16x8*)(dst + j * 8) = v;
      }
    }
    if (tid < 128) {
      const unsigned short* src = qkv + base + (long)(c0 + tid) * 3456 + (32 + h) * 72;
      u16x8 w[9];
#pragma unroll
      for (int j = 0; j < 9; j++) w[j] = *(const u16x8*)(src + j * 8);
#pragma unroll
      for (int j = 0; j < 9; j++)
#pragma unroll
        for (int e = 0; e < 8; e++) V_s[(j * 8 + e) * 136 + tid] = w[j][e];
    }
    __syncthreads();

#pragma unroll
    for (int k32 = 0; k32 < 4; k32++) {
#pragma unroll
      for (int kt = 0; kt < 2; kt++) {
        bf16x8 kf[3];
#pragma unroll
        for (int ds = 0; ds < 3; ds++)
          kf[ds] = *(const bf16x8*)((const char*)K_s +
                     ((k32 * 32 + kt * 16 + l15) * 104 + ds * 32 + hi * 8) * 2);
#pragma unroll
        for (int qt = 0; qt < 4; qt++) {
          f32x4 st = {};
#pragma unroll
          for (int ds = 0; ds < 3; ds++) st = MFMA_BF16(kf[ds], qf[qt][ds], st, 0, 0, 0);
          u16x4 pw;
#pragma unroll
          for (int r = 0; r < 4; r++) {
            float p = exp2f(st[r] * SC2);
            lsum[qt] += p;
            pw[r] = f2bf(p);
          }
          *(u16x4*)&P_s[((wid * 4 + qt) * 16 + l15) * 40 + kt * 16 + hi * 4] = pw;
        }
      }
      bf16x8 pf[4];
#pragma unroll
      for (int qt = 0; qt < 4; qt++)
        pf[qt] = *(const bf16x8*)&P_s[((wid * 4 + qt) * 16 + l15) * 40 + hi * 8];
#pragma unroll
      for (int dt = 0; dt < 5; dt++) {
        bf16x8 vf = *(const bf16x8*)&V_s[(dt * 16 + l15) * 136 + k32 * 32 + hi * 8];
#pragma unroll
        for (int qt = 0; qt < 4; qt++) ot[dt][qt] = MFMA_BF16(vf, pf[qt], ot[dt][qt], 0, 0, 0);
      }
    }
    __syncthreads();
  }

#pragma unroll
  for (int qt = 0; qt < 4; qt++) {
    float s = lsum[qt];
    s += __shfl_xor(s, 16);
    s += __shfl_xor(s, 32);
    lsum[qt] = 1.0f / s;
  }
#pragma unroll
  for (int dt = 0; dt < 5; dt++)
#pragma unroll
    for (int qt = 0; qt < 4; qt++)
#pragma unroll
      for (int r = 0; r < 4; r++) {
        int d = dt * 16 + hi * 4 + r;
        if (d < 72) {
          long row = (long)b * 825 + 57 + g * 256 + wid * 64 + qt * 16 + l15;
          o[row * 1152 + h * 72 + d] = f2bf(ot[dt][qt][r] * lsum[qt]);
        }
      }
}

// ---- act attention: one block per (h, b); kv rows compact (769 per batch) ----
__global__ void __launch_bounds__(256) attn_act(const unsigned short* __restrict__ kv,
                                                const unsigned short* __restrict__ qa,
                                                unsigned short* __restrict__ o) {
  int h = blockIdx.x, b = blockIdx.y;
  __shared__ unsigned short K_s[128 * 104];
  __shared__ unsigned short V_s[80 * 136];
  __shared__ unsigned short P_s[4 * 16 * 40];
  int tid = threadIdx.x, lane = tid & 63, wid = tid >> 6;
  int l15 = lane & 15, hi = lane >> 4;
  const float SC2 = 0.11785113019775793f * 1.4426950408889634f;
  const int LIM = 769;

  bf16x8 qf[3];
  {
    int q = wid * 16 + l15; if (q > 56) q = 56;
#pragma unroll
    for (int ds = 0; ds < 3; ds++) {
      int d = ds * 32 + hi * 8;
      if (d < 72)
        qf[ds] = *(const bf16x8*)(qa + (long)(b * 57 + q) * 1152 + h * 72 + d);
      else {
        u16x8 z = {0, 0, 0, 0, 0, 0, 0, 0};
        qf[ds] = __builtin_bit_cast(bf16x8, z);
      }
    }
  }

  f32x4 ot[5] = {};
  float lsum = 0.f;
  const long kbase = (long)b * 769;

  for (int c0 = 0; c0 < LIM; c0 += 128) {
    int valid = LIM - c0; if (valid > 128) valid = 128;
    {
      int r = tid >> 1, hf = tid & 1;
      int rr = r < valid ? r : valid - 1;
      const unsigned short* src = kv + (kbase + c0 + rr) * 2304 + h * 72 + hf * 48;
      unsigned short* dst = &K_s[r * 104 + hf * 48];
#pragma unroll
      for (int j = 0; j < 6; j++) {
        int col = hf * 48 + j * 8;
        u16x8 v = {0, 0, 0, 0, 0, 0, 0, 0};
        if (col < 72) v = *(const u16x8*)(src + j * 8);
        *(u16x8*)(dst + j * 8) = v;
      }
    }
    if (tid < 128) {
      int rr = tid < valid ? tid : valid - 1;
      const unsigned short* src = kv + (kbase + c0 + rr) * 2304 + (16 + h) * 72;
      u16x8 w[9];
#pragma unroll
      for (int j = 0; j < 9; j++) w[j] = *(const u16x8*)(src + j * 8);
#pragma unroll
      for (int j = 0; j < 9; j++)
#pragma unroll
        for (int e = 0; e < 8; e++) V_s[(j * 8 + e) * 136 + tid] = w[j][e];
    }
    __syncthreads();

#pragma unroll
    for (int k32 = 0; k32 < 4; k32++) {
#pragma unroll
      for (int kt = 0; kt < 2; kt++) {
        bf16x8 kf[3];
#pragma unroll
        for (int ds = 0; ds < 3; ds++)
          kf[ds] = *(const bf16x8*)((const char*)K_s +
                     ((k32 * 32 + kt * 16 + l15) * 104 + ds * 32 + hi * 8) * 2);
        f32x4 st = {};
#pragma unroll
        for (int ds = 0; ds < 3; ds++) st = MFMA_BF16(kf[ds], qf[ds], st, 0, 0, 0);
        u16x4 pw;
#pragma unroll
        for (int r = 0; r < 4; r++) {
          int kg = c0 + k32 * 32 + kt * 16 + hi * 4 + r;
          float p = (kg < LIM) ? exp2f(st[r] * SC2) : 0.f;
          lsum += p;
          pw[r] = f2bf(p);
        }
        *(u16x4*)&P_s[(wid * 16 + l15) * 40 + kt * 16 + hi * 4] = pw;
      }
      bf16x8 pf = *(const bf16x8*)&P_s[(wid * 16 + l15) * 40 + hi * 8];
#pragma unroll
      for (int dt = 0; dt < 5; dt++) {
        bf16x8 vf = *(const bf16x8*)&V_s[(dt * 16 + l15) * 136 + k32 * 32 + hi * 8];
        ot[dt] = MFMA_BF16(vf, pf, ot[dt], 0, 0, 0);
      }
    }
    __syncthreads();
  }

  {
    float s = lsum;
    s += __shfl_xor(s, 16);
    s += __shfl_xor(s, 32);
    lsum = 1.0f / s;
  }
  int q = wid * 16 + l15;
#pragma unroll
  for (int dt = 0; dt < 5; dt++)
#pragma unroll
    for (int r = 0; r < 4; r++) {
      int d = dt * 16 + hi * 4 + r;
      if (d < 72 && q < 57)
        o[((long)b * 825 + q) * 1152 + h * 72 + d] = f2bf(ot[dt][r] * lsum);
    }
}

extern "C" void kernel_launch(void* const* d_in, const int* in_sizes, int n_in,
                              void* d_out, int out_size, void* d_ws, size_t ws_size,
                              hipStream_t stream) {
  const float* x     = (const float*)d_in[0];
  const float* w_qkv = (const float*)d_in[1];
  const float* w_q   = (const float*)d_in[2];
  const float* w_kv  = (const float*)d_in[3];
  const float* w_pn  = (const float*)d_in[4];
  const float* b_pn  = (const float*)d_in[5];
  const float* w_pa  = (const float*)d_in[6];
  const float* b_pa  = (const float*)d_in[7];

  char* ws = (char*)d_ws;
  unsigned short* xb    = (unsigned short*)ws; ws += (size_t)26400 * 1152 * 2;
  unsigned short* wqkvb = (unsigned short*)ws; ws += (size_t)3456 * 1152 * 2;
  unsigned short* wqb   = (unsigned short*)ws; ws += (size_t)1152 * 1152 * 2;
  unsigned short* wkvb  = (unsigned short*)ws; ws += (size_t)2304 * 1152 * 2;
  unsigned short* wpnb  = (unsigned short*)ws; ws += (size_t)1152 * 1152 * 2;
  unsigned short* wpab  = (unsigned short*)ws; ws += (size_t)1152 * 1152 * 2;
  unsigned short* qkvw  = (unsigned short*)ws; ws += (size_t)24576 * 3456 * 2;
  unsigned short* kvw   = (unsigned short*)ws; ws += (size_t)24608 * 2304 * 2;
  unsigned short* qw    = (unsigned short*)ws; ws += (size_t)1824 * 1152 * 2;
  unsigned short* attnw = (unsigned short*)ws; ws += (size_t)26400 * 1152 * 2;

  // one fused cast for all 6 fp32->bf16 conversions
  cast_all<<<20034, 256, 0, stream>>>(x, w_qkv, w_q, w_kv, w_pn, w_pa,
                                      xb, wqkvb, wqb, wkvb, wpnb, wpab);

  // fused front GEMMs: qkv | kv (row-trimmed) | q_act
  gemm_front<<<2257, 512, 0, stream>>>(xb, wqkvb, wkvb, wqb, qkvw, kvw, qw);

  attn_non<<<dim3(16, 3, 32), 256, 0, stream>>>(qkvw, attnw);
  attn_act<<<dim3(16, 32), 256, 0, stream>>>(kvw, qw, attnw);

  // fused projections into d_out (fp32), act blocks first
  gemm_proj<<<520, 512, 0, stream>>>(attnw, wpnb, wpab, (float*)d_out, b_pn, b_pa);
}

// Round 21
// 642.396 us; speedup vs baseline: 1.0314x; 1.0314x over previous
//
#include <hip/hip_runtime.h>

typedef __attribute__((ext_vector_type(8))) __bf16 bf16x8;
typedef __attribute__((ext_vector_type(4))) float f32x4;
typedef __attribute__((ext_vector_type(4))) unsigned short u16x4;
typedef __attribute__((ext_vector_type(8))) unsigned short u16x8;

#define MFMA_BF16 __builtin_amdgcn_mfma_f32_16x16x32_bf16

__device__ __forceinline__ unsigned short f2bf(float f) {
  union { float f; unsigned u; } v; v.f = f;
  unsigned r = v.u + 0x7FFFu + ((v.u >> 16) & 1u);
  return (unsigned short)(r >> 16);
}

__device__ __forceinline__ void gload16(const void* g, void* l) {
  __builtin_amdgcn_global_load_lds(
      (const __attribute__((address_space(1))) unsigned int*)g,
      (__attribute__((address_space(3))) unsigned int*)l, 16, 0, 0);
}

// ---- fused cast: all 6 fp32->bf16 conversions in one launch ----
__device__ __forceinline__ void cast8(const float* __restrict__ in,
                                      unsigned short* __restrict__ out, long i) {
  long base = i * 8;
  float4 a = *(const float4*)(in + base);
  float4 b = *(const float4*)(in + base + 4);
  u16x8 o;
  o[0] = f2bf(a.x); o[1] = f2bf(a.y); o[2] = f2bf(a.z); o[3] = f2bf(a.w);
  o[4] = f2bf(b.x); o[5] = f2bf(b.y); o[6] = f2bf(b.z); o[7] = f2bf(b.w);
  *(u16x8*)(out + base) = o;
}

__global__ void __launch_bounds__(256) cast_all(
    const float* __restrict__ x, const float* __restrict__ wqkv,
    const float* __restrict__ wq, const float* __restrict__ wkv,
    const float* __restrict__ wpn, const float* __restrict__ wpa,
    unsigned short* __restrict__ xb, unsigned short* __restrict__ wqkvb,
    unsigned short* __restrict__ wqb, unsigned short* __restrict__ wkvb,
    unsigned short* __restrict__ wpnb, unsigned short* __restrict__ wpab) {
  const long c0 = 3801600, c1 = 4299264, c2 = 4465152, c3 = 4796928,
             c4 = 4962816, c5 = 5128704;
  long i = (long)blockIdx.x * 256 + threadIdx.x;
  if (i >= c5) return;
  if (i < c0)      cast8(x,    xb,    i);
  else if (i < c1) cast8(wqkv, wqkvb, i - c0);
  else if (i < c2) cast8(wq,   wqb,   i - c1);
  else if (i < c3) cast8(wkv,  wkvb,  i - c2);
  else if (i < c4) cast8(wpn,  wpnb,  i - c3);
  else             cast8(wpa,  wpab,  i - c4);
}

// row remapping: 0 = identity, 1 = b*825 + 57 + (m % 768), 2 = b*825 + (m % 57),
//                3 = b*825 + 56 + (m % 769)
template <int REMAP>
__device__ __forceinline__ long remap_row(int m) {
  if (REMAP == 1) { int b = m / 768; return (long)b * 825 + 57 + (m - b * 768); }
  if (REMAP == 2) { int b = m / 57;  return (long)b * 825 + (m - b * 57); }
  if (REMAP == 3) { int b = m / 769; return (long)b * 825 + 56 + (m - b * 769); }
  return m;
}

// ===== 256x256 tile, BK=64, 8-wave, 2-phase/K-tile, register-pipelined fA =====
// Final verified configuration (r17/r19, 644-651 us): T19 interleave
// {1 ds_read(fA), 4 MFMA} x 8 then 4 fB ds_reads; no setprio (measured negative
// with the SGB interleave).
template <int REMAP, bool PROJ>
__device__ __forceinline__ void gemm_body(unsigned short* L, int orig, int gx, int nwg,
                                          const unsigned short* __restrict__ A,
                                          const unsigned short* __restrict__ Bw,
                                          void* __restrict__ Cout,
                                          const float* __restrict__ bias,
                                          int M, int N) {
  const int K = 1152;
  unsigned short* Al = L;
  unsigned short* Bl = L + 32768;
  int tid = threadIdx.x;
  int lane = tid & 63;
  int wid = tid >> 6;
  int l15 = lane & 15, hi = lane >> 4;
  int wm = wid >> 2, wn = wid & 3;

  // bijective XCD swizzle within this segment
  int q8 = nwg >> 3, r8 = nwg & 7;
  int xcd = orig & 7, off = orig >> 3;
  int wgid = (xcd < r8 ? xcd * (q8 + 1) : r8 * (q8 + 1) + (xcd - r8) * q8) + off;
  int bn = wgid % gx, bm = wgid / gx;
  int m0 = bm * 256, n0 = bn * 256;

  // staging geometry: thread stages 16B at slot-bytes tid*16 and tid*16+8192
  int rlo = tid >> 2;
  int cg = ((tid & 3) - (tid >> 3)) & 3;
  int ma0 = m0 + rlo;       if (ma0 > M - 1) ma0 = M - 1;
  int ma1 = m0 + rlo + 128; if (ma1 > M - 1) ma1 = M - 1;
  const unsigned short* aptr0 = A + remap_row<REMAP>(ma0) * K + cg * 8;
  const unsigned short* aptr1 = A + remap_row<REMAP>(ma1) * K + cg * 8;
  int nb0 = n0 + rlo;       if (nb0 > N - 1) nb0 = N - 1;
  int nb1 = n0 + rlo + 128; if (nb1 > N - 1) nb1 = N - 1;
  const unsigned short* bptr0 = Bw + (long)nb0 * K + cg * 8;
  const unsigned short* bptr1 = Bw + (long)nb1 * K + cg * 8;
  unsigned ldst = (unsigned)tid * 8;

  unsigned short* Ad = Al + ldst;
  unsigned short* Bd = Bl + ldst;

  const int cl = (hi + (l15 >> 1)) & 3;
  const unsigned short* arb[4];
  const unsigned short* brb[4];
#pragma unroll
  for (int f = 0; f < 4; ++f) {
    arb[f] = Al + (wm * 128 + f * 16 + l15) * 32 + cl * 8;
    brb[f] = Bl + (wn * 64 + f * 16 + l15) * 32 + cl * 8;
  }

#define STAGE(P)                                                        \
  {                                                                     \
    gload16(aptr0 + (P) * 32, Ad + (((P) & 3) << 13));                  \
    gload16(aptr1 + (P) * 32, Ad + ((((P) & 3) << 13)) + 4096);         \
    gload16(bptr0 + (P) * 32, Bd + (((P) & 3) << 13));                  \
    gload16(bptr1 + (P) * 32, Bd + ((((P) & 3) << 13)) + 4096);         \
  }
#define READ_FA(P, S)                                                   \
  {                                                                     \
    _Pragma("unroll") for (int f = 0; f < 8; ++f)                       \
        fA[S][f] = *(const bf16x8*)(arb[f & 3] + (((P) & 3) << 13) + (f >> 2) * 2048); \
  }
#define READ_FB(P)                                                      \
  {                                                                     \
    _Pragma("unroll") for (int f = 0; f < 4; ++f)                       \
        fB[f] = *(const bf16x8*)(brb[f] + (((P) & 3) << 13));           \
  }

  STAGE(0); STAGE(1); STAGE(2);
  __builtin_amdgcn_sched_barrier(0);
  asm volatile("s_waitcnt vmcnt(4)" ::: "memory");
  __builtin_amdgcn_s_barrier();
  __builtin_amdgcn_sched_barrier(0);

  bf16x8 fA[2][8];
  bf16x8 fB[4];
  READ_FA(0, 0);
  READ_FB(0);
  f32x4 acc[8][4] = {};

#pragma unroll
  for (int p = 0; p < 36; ++p) {
    const int cur = p & 1;
    if (p < 35) READ_FA(p + 1, cur ^ 1);     // next-phase A frags, independent regs
#pragma unroll
    for (int fm = 0; fm < 8; ++fm)
#pragma unroll
      for (int fn = 0; fn < 4; ++fn)
        acc[fm][fn] = MFMA_BF16(fA[cur][fm], fB[fn], acc[fm][fn], 0, 0, 0);
    if (p < 35) READ_FB(p + 1);              // B frags (WAR-ordered after MFMA)
    if (p <= 32) STAGE(p + 3);
    if (p < 35) {
      // T19: emit {1 fA ds_read, 4 MFMA} x 8, then the 4 fB reads (WAR keeps them late)
#pragma unroll
      for (int g = 0; g < 8; ++g) {
        __builtin_amdgcn_sched_group_barrier(0x100, 1, 0);
        __builtin_amdgcn_sched_group_barrier(0x008, 4, 0);
      }
      __builtin_amdgcn_sched_group_barrier(0x100, 4, 0);
    }
    if (p <= 32)      asm volatile("s_waitcnt vmcnt(4)" ::: "memory");
    else if (p == 33) asm volatile("s_waitcnt vmcnt(0)" ::: "memory");
    if (p < 35) {
      __builtin_amdgcn_sched_barrier(0);
      __builtin_amdgcn_s_barrier();
      __builtin_amdgcn_sched_barrier(0);
    }
  }
#undef STAGE
#undef READ_FA
#undef READ_FB

  // ======== epilogue via per-wave-private LDS region -> coalesced 16B stores ========
  if (!PROJ) {
    unsigned short* reg = L + wid * 8192;
#pragma unroll
    for (int a = 0; a < 8; ++a) {
#pragma unroll
      for (int fn = 0; fn < 4; ++fn) {
        int rbase = a * 16 + hi * 4;
#pragma unroll
        for (int r = 0; r < 4; ++r) {
          int row = rbase + r;
          int ch = (fn * 2 + (l15 >> 3)) ^ (row & 7);
          reg[row * 64 + ch * 8 + (l15 & 7)] = f2bf(acc[a][fn][r]);
        }
      }
    }
#pragma unroll
    for (int i = 0; i < 16; ++i) {
      int rr = i * 8 + (lane >> 3);
      int ch = (lane & 7) ^ (rr & 7);
      u16x8 v = *(const u16x8*)(reg + rr * 64 + ch * 8);
      int m = m0 + wm * 128 + rr;
      int n = n0 + wn * 64 + (lane & 7) * 8;
      if (m < M && n < N)
        *(u16x8*)((unsigned short*)Cout + (long)m * N + n) = v;
    }
  } else {
    float* regf = (float*)L + wid * 4096;
    float bv[4];
#pragma unroll
    for (int fn = 0; fn < 4; ++fn) {
      int n = n0 + wn * 64 + fn * 16 + l15;
      bv[fn] = bias[n < N ? n : N - 1];
    }
#pragma unroll
    for (int half = 0; half < 2; ++half) {
#pragma unroll
      for (int a4 = 0; a4 < 4; ++a4) {
#pragma unroll
        for (int fn = 0; fn < 4; ++fn) {
          int rbase = a4 * 16 + hi * 4;
#pragma unroll
          for (int r = 0; r < 4; ++r)
            regf[(rbase + r) * 64 + fn * 16 + l15] = acc[half * 4 + a4][fn][r] + bv[fn];
        }
      }
#pragma unroll
      for (int i = 0; i < 16; ++i) {
        int rr = i * 4 + (lane >> 4);
        int cc = (lane & 15) * 4;
        f32x4 v = *(const f32x4*)(regf + rr * 64 + cc);
        int m = m0 + wm * 128 + half * 64 + rr;
        int n = n0 + wn * 64 + cc;
        if (m < M && n < N)
          *(f32x4*)((float*)Cout + remap_row<REMAP>(m) * N + n) = v;
      }
      if (half == 0) asm volatile("s_waitcnt lgkmcnt(0)" ::: "memory");
    }
  }
}

// fused front GEMMs: qkv (1344 blocks) | kv (873, trimmed rows) | q_act (40)
__global__ void __launch_bounds__(512, 2) gemm_front(
    const unsigned short* __restrict__ xb, const unsigned short* __restrict__ wqkvb,
    const unsigned short* __restrict__ wkvb, const unsigned short* __restrict__ wqb,
    unsigned short* __restrict__ qkvw, unsigned short* __restrict__ kvw,
    unsigned short* __restrict__ qw) {
  __shared__ unsigned short L[65536];  // 128 KiB, shared by all branches
  int bid = blockIdx.x;
  if (bid < 1344)
    gemm_body<1, false>(L, bid, 14, 1344, xb, wqkvb, qkvw, nullptr, 24576, 3456);
  else if (bid < 2217)
    gemm_body<3, false>(L, bid - 1344, 9, 873, xb, wkvb, kvw, nullptr, 24608, 2304);
  else
    gemm_body<2, false>(L, bid - 2217, 5, 40, xb, wqb, qw, nullptr, 1824, 1152);
}

// fused projections: proj_act (40 blocks, first) | proj_non (480)
__global__ void __launch_bounds__(512, 2) gemm_proj(
    const unsigned short* __restrict__ attnw, const unsigned short* __restrict__ wpnb,
    const unsigned short* __restrict__ wpab, float* __restrict__ out,
    const float* __restrict__ bpn, const float* __restrict__ bpa) {
  __shared__ unsigned short L[65536];
  int bid = blockIdx.x;
  if (bid < 40)
    gemm_body<2, true>(L, bid, 5, 40, attnw, wpab, out, bpa, 1824, 1152);
  else
    gemm_body<1, true>(L, bid - 40, 5, 480, attnw, wpnb, out, bpn, 24576, 1152);
}

// ---- non-act attention: one block per (h, g, b); 4 waves, each owns 64 q rows ----
__global__ void __launch_bounds__(256) attn_non(const unsigned short* __restrict__ qkv,
                                                unsigned short* __restrict__ o) {
  int h = blockIdx.x, g = blockIdx.y, b = blockIdx.z;
  __shared__ unsigned short K_s[128 * 104];
  __shared__ unsigned short V_s[80 * 136];
  __shared__ unsigned short P_s[16 * 16 * 40];
  int tid = threadIdx.x, lane = tid & 63, wid = tid >> 6;
  int l15 = lane & 15, hi = lane >> 4;
  const long base = (long)((b * 3 + g) * 256) * 3456;
  const float SC2 = 0.11785113019775793f * 1.4426950408889634f;

  bf16x8 qf[4][3];
#pragma unroll
  for (int qt = 0; qt < 4; qt++)
#pragma unroll
    for (int ds = 0; ds < 3; ds++) {
      int q = wid * 64 + qt * 16 + l15;
      int d = ds * 32 + hi * 8;
      if (d < 72)
        qf[qt][ds] = *(const bf16x8*)(qkv + base + (long)q * 3456 + h * 72 + d);
      else {
        u16x8 z = {0, 0, 0, 0, 0, 0, 0, 0};
        qf[qt][ds] = __builtin_bit_cast(bf16x8, z);
      }
    }

  f32x4 ot[5][4] = {};
  float lsum[4] = {0.f, 0.f, 0.f, 0.f};

  for (int c0 = 0; c0 < 256; c0 += 128) {
    {
      int r = tid >> 1, hf = tid & 1;
      const unsigned short* src = qkv + base + (long)(c0 + r) * 3456 + (16 + h) * 72 + hf * 48;
      unsigned short* dst = &K_s[r * 104 + hf * 48];
#pragma unroll
      for (int j = 0; j < 6; j++) {
        int col = hf * 48 + j * 8;
        u16x8 v = {0, 0, 0, 0, 0, 0, 0, 0};
        if (col < 72) v = *(const u16x8*)(src + j * 8);
        *(u16x8*)(dst + j * 8) = v;
      }
    }
    if (tid < 128) {
      const unsigned short* src = qkv + base + (long)(c0 + tid) * 3456 + (32 + h) * 72;
      u16x8 w[9];
#pragma unroll
      for (int j = 0; j < 9; j++) w[j] = *(const u16x8*)(src + j * 8);
#pragma unroll
      for (int j = 0; j < 9; j++)
#pragma unroll
        for (int e = 0; e < 8; e++) V_s[(j * 8 + e) * 136 + tid] = w[j][e];
    }
    __syncthreads();

#pragma unroll
    for (int k32 = 0; k32 < 4; k32++) {
#pragma unroll
      for (int kt = 0; kt < 2; kt++) {
        bf16x8 kf[3];
#pragma unroll
        for (int ds = 0; ds < 3; ds++)
          kf[ds] = *(const bf16x8*)((const char*)K_s +
                     ((k32 * 32 + kt * 16 + l15) * 104 + ds * 32 + hi * 8) * 2);
#pragma unroll
        for (int qt = 0; qt < 4; qt++) {
          f32x4 st = {};
#pragma unroll
          for (int ds = 0; ds < 3; ds++) st = MFMA_BF16(kf[ds], qf[qt][ds], st, 0, 0, 0);
          u16x4 pw;
#pragma unroll
          for (int r = 0; r < 4; r++) {
            float p = exp2f(st[r] * SC2);
            lsum[qt] += p;
            pw[r] = f2bf(p);
          }
          *(u16x4*)&P_s[((wid * 4 + qt) * 16 + l15) * 40 + kt * 16 + hi * 4] = pw;
        }
      }
      bf16x8 pf[4];
#pragma unroll
      for (int qt = 0; qt < 4; qt++)
        pf[qt] = *(const bf16x8*)&P_s[((wid * 4 + qt) * 16 + l15) * 40 + hi * 8];
#pragma unroll
      for (int dt = 0; dt < 5; dt++) {
        bf16x8 vf = *(const bf16x8*)&V_s[(dt * 16 + l15) * 136 + k32 * 32 + hi * 8];
#pragma unroll
        for (int qt = 0; qt < 4; qt++) ot[dt][qt] = MFMA_BF16(vf, pf[qt], ot[dt][qt], 0, 0, 0);
      }
    }
    __syncthreads();
  }

#pragma unroll
  for (int qt = 0; qt < 4; qt++) {
    float s = lsum[qt];
    s += __shfl_xor(s, 16);
    s += __shfl_xor(s, 32);
    lsum[qt] = 1.0f / s;
  }
#pragma unroll
  for (int dt = 0; dt < 5; dt++)
#pragma unroll
    for (int qt = 0; qt < 4; qt++)
#pragma unroll
      for (int r = 0; r < 4; r++) {
        int d = dt * 16 + hi * 4 + r;
        if (d < 72) {
          long row = (long)b * 825 + 57 + g * 256 + wid * 64 + qt * 16 + l15;
          o[row * 1152 + h * 72 + d] = f2bf(ot[dt][qt][r] * lsum[qt]);
        }
      }
}

// ---- act attention: one block per (h, b); kv rows compact (769 per batch) ----
__global__ void __launch_bounds__(256) attn_act(const unsigned short* __restrict__ kv,
                                                const unsigned short* __restrict__ qa,
                                                unsigned short* __restrict__ o) {
  int h = blockIdx.x, b = blockIdx.y;
  __shared__ unsigned short K_s[128 * 104];
  __shared__ unsigned short V_s[80 * 136];
  __shared__ unsigned short P_s[4 * 16 * 40];
  int tid = threadIdx.x, lane = tid & 63, wid = tid >> 6;
  int l15 = lane & 15, hi = lane >> 4;
  const float SC2 = 0.11785113019775793f * 1.4426950408889634f;
  const int LIM = 769;

  bf16x8 qf[3];
  {
    int q = wid * 16 + l15; if (q > 56) q = 56;
#pragma unroll
    for (int ds = 0; ds < 3; ds++) {
      int d = ds * 32 + hi * 8;
      if (d < 72)
        qf[ds] = *(const bf16x8*)(qa + (long)(b * 57 + q) * 1152 + h * 72 + d);
      else {
        u16x8 z = {0, 0, 0, 0, 0, 0, 0, 0};
        qf[ds] = __builtin_bit_cast(bf16x8, z);
      }
    }
  }

  f32x4 ot[5] = {};
  float lsum = 0.f;
  const long kbase = (long)b * 769;

  for (int c0 = 0; c0 < LIM; c0 += 128) {
    int valid = LIM - c0; if (valid > 128) valid = 128;
    {
      int r = tid >> 1, hf = tid & 1;
      int rr = r < valid ? r : valid - 1;
      const unsigned short* src = kv + (kbase + c0 + rr) * 2304 + h * 72 + hf * 48;
      unsigned short* dst = &K_s[r * 104 + hf * 48];
#pragma unroll
      for (int j = 0; j < 6; j++) {
        int col = hf * 48 + j * 8;
        u16x8 v = {0, 0, 0, 0, 0, 0, 0, 0};
        if (col < 72) v = *(const u16x8*)(src + j * 8);
        *(u16x8*)(dst + j * 8) = v;
      }
    }
    if (tid < 128) {
      int rr = tid < valid ? tid : valid - 1;
      const unsigned short* src = kv + (kbase + c0 + rr) * 2304 + (16 + h) * 72;
      u16x8 w[9];
#pragma unroll
      for (int j = 0; j < 9; j++) w[j] = *(const u16x8*)(src + j * 8);
#pragma unroll
      for (int j = 0; j < 9; j++)
#pragma unroll
        for (int e = 0; e < 8; e++) V_s[(j * 8 + e) * 136 + tid] = w[j][e];
    }
    __syncthreads();

#pragma unroll
    for (int k32 = 0; k32 < 4; k32++) {
#pragma unroll
      for (int kt = 0; kt < 2; kt++) {
        bf16x8 kf[3];
#pragma unroll
        for (int ds = 0; ds < 3; ds++)
          kf[ds] = *(const bf16x8*)((const char*)K_s +
                     ((k32 * 32 + kt * 16 + l15) * 104 + ds * 32 + hi * 8) * 2);
        f32x4 st = {};
#pragma unroll
        for (int ds = 0; ds < 3; ds++) st = MFMA_BF16(kf[ds], qf[ds], st, 0, 0, 0);
        u16x4 pw;
#pragma unroll
        for (int r = 0; r < 4; r++) {
          int kg = c0 + k32 * 32 + kt * 16 + hi * 4 + r;
          float p = (kg < LIM) ? exp2f(st[r] * SC2) : 0.f;
          lsum += p;
          pw[r] = f2bf(p);
        }
        *(u16x4*)&P_s[(wid * 16 + l15) * 40 + kt * 16 + hi * 4] = pw;
      }
      bf16x8 pf = *(const bf16x8*)&P_s[(wid * 16 + l15) * 40 + hi * 8];
#pragma unroll
      for (int dt = 0; dt < 5; dt++) {
        bf16x8 vf = *(const bf16x8*)&V_s[(dt * 16 + l15) * 136 + k32 * 32 + hi * 8];
        ot[dt] = MFMA_BF16(vf, pf, ot[dt], 0, 0, 0);
      }
    }
    __syncthreads();
  }

  {
    float s = lsum;
    s += __shfl_xor(s, 16);
    s += __shfl_xor(s, 32);
    lsum = 1.0f / s;
  }
  int q = wid * 16 + l15;
#pragma unroll
  for (int dt = 0; dt < 5; dt++)
#pragma unroll
    for (int r = 0; r < 4; r++) {
      int d = dt * 16 + hi * 4 + r;
      if (d < 72 && q < 57)
        o[((long)b * 825 + q) * 1152 + h * 72 + d] = f2bf(ot[dt][r] * lsum);
    }
}

extern "C" void kernel_launch(void* const* d_in, const int* in_sizes, int n_in,
                              void* d_out, int out_size, void* d_ws, size_t ws_size,
                              hipStream_t stream) {
  const float* x     = (const float*)d_in[0];
  const float* w_qkv = (const float*)d_in[1];
  const float* w_q   = (const float*)d_in[2];
  const float* w_kv  = (const float*)d_in[3];
  const float* w_pn  = (const float*)d_in[4];
  const float* b_pn  = (const float*)d_in[5];
  const float* w_pa  = (const float*)d_in[6];
  const float* b_pa  = (const float*)d_in[7];

  char* ws = (char*)d_ws;
  unsigned short* xb    = (unsigned short*)ws; ws += (size_t)26400 * 1152 * 2;
  unsigned short* wqkvb = (unsigned short*)ws; ws += (size_t)3456 * 1152 * 2;
  unsigned short* wqb   = (unsigned short*)ws; ws += (size_t)1152 * 1152 * 2;
  unsigned short* wkvb  = (unsigned short*)ws; ws += (size_t)2304 * 1152 * 2;
  unsigned short* wpnb  = (unsigned short*)ws; ws += (size_t)1152 * 1152 * 2;
  unsigned short* wpab  = (unsigned short*)ws; ws += (size_t)1152 * 1152 * 2;
  unsigned short* qkvw  = (unsigned short*)ws; ws += (size_t)24576 * 3456 * 2;
  unsigned short* kvw   = (unsigned short*)ws; ws += (size_t)24608 * 2304 * 2;
  unsigned short* qw    = (unsigned short*)ws; ws += (size_t)1824 * 1152 * 2;
  unsigned short* attnw = (unsigned short*)ws; ws += (size_t)26400 * 1152 * 2;

  // one fused cast for all 6 fp32->bf16 conversions
  cast_all<<<20034, 256, 0, stream>>>(x, w_qkv, w_q, w_kv, w_pn, w_pa,
                                      xb, wqkvb, wqb, wkvb, wpnb, wpab);

  // fused front GEMMs: qkv | kv (row-trimmed) | q_act
  gemm_front<<<2257, 512, 0, stream>>>(xb, wqkvb, wkvb, wqb, qkvw, kvw, qw);

  attn_non<<<dim3(16, 3, 32), 256, 0, stream>>>(qkvw, attnw);
  attn_act<<<dim3(16, 32), 256, 0, stream>>>(kvw, qw, attnw);

  // fused projections into d_out (fp32), act blocks first
  gemm_proj<<<520, 512, 0, stream>>>(attnw, wpnb, wpab, (float*)d_out, b_pn, b_pa);
}